// Round 7
// baseline (2038.815 us; speedup 1.0000x reference)
//
#include <hip/hip_runtime.h>
#include <math.h>

// RecursiveAttentiveEncoder — fused-tree MFMA, R7.
// R6 post-mortem (870us tree_k): 140KB LDS -> 1 blk/CU -> 1 wave/SIMD (all
// latency exposed, MfmaUtil 11.5%); stride-136 LDS rows -> 2.1e7 bank-conflict
// cycles; per-group L2 weight streaming unhidden. R7: TPB=16 + 16KB H -> 67KB
// LDS -> 2 blk/CU (2 waves/SIMD); unpadded 256B rows with XOR chunk swizzle
// (conflict-free by construction); leaf gathers hoisted into sort; MR=32
// groups; A-loads = 4 bases + immediate offsets for deep pipelining.
// Math identical to the verified R5/R6 engine (absmax 1.2e-4).

typedef unsigned short u16;
typedef unsigned int   u32;
typedef unsigned long long u64;
typedef __attribute__((ext_vector_type(8))) short v8s;   // 8 bf16 (4 VGPRs)
typedef __attribute__((ext_vector_type(4))) float f32x4; // MFMA acc

__device__ __forceinline__ float b2f(u16 u) { return __uint_as_float(((u32)u) << 16); }
__device__ __forceinline__ u16 f2b(float f) {
  f = (f == f) ? f : 0.f;                    // NaN squash (hygiene)
  u32 x = __float_as_uint(f);
  u32 r = x + 0x7fffu + ((x >> 16) & 1u);
  return (u16)(r >> 16);
}

#define NTREE 34816   // B*T_TREES = 1024*34
#define RLEAF 9216    // B*(GT_MAX+1)
#define TPB   16      // trees per block in tree_k

// tree_k LDS layout, u16 units. Level rows: 128 bf16 = 16 x 16B chunks,
// stored swizzled (no pad). H rows: 256 bf16 = 32 chunks, swizzled.
#define OFF_A  0      // 128 rows * 128 = 16384  (lvl0 out, lvl2 out)
#define OFF_B  16384  // 64 rows * 128  = 8192   (lvl1 out)
#define OFF_H  24576  // 32 rows * 256  = 8192   (phase-1 h scratch)
#define OFF_L  32768  // bin lists 4 * 128 = 512
#define OFF_LI 33280  // lvl0 leaf-idx pairs: 128*2 = 256
#define OFF_C  33536  // 4 int counters (16 u16)
#define SMEM_U16 33552              // 67104 B -> 2 blocks/CU

// swizzled u16 offset of (row r, 16B-chunk c) for 16-chunk rows
__device__ __forceinline__ int sw16(int r, int c) {
  return ((r << 4) + (c ^ ((r ^ (r >> 4)) & 15))) << 3;
}
// swizzled u16 offset for 32-chunk (256-wide) H rows
__device__ __forceinline__ int sw32(int r, int c) {
  return ((r << 5) + (c ^ (r & 31))) << 3;
}

// ==================== leaf-stage expert sort ====================
__global__ __launch_bounds__(256) void leaf_perm_k(
    const int* __restrict__ lf, int* __restrict__ cnt, int* __restrict__ perm)
{
  const int gid = blockIdx.x * 256 + threadIdx.x;   // 36*256 = 9216 exact
  const int id = lf[gid];
  const int lane = threadIdx.x & 63;
  for (int e = 0; e < 3; ++e) {
    u64 m = __ballot(id == e);
    if (!m) continue;
    int leader = __builtin_ctzll(m);
    int bp = 0;
    if (lane == leader) bp = atomicAdd(&cnt[e], (int)__popcll(m));
    bp = __shfl(bp, leader);
    if (id == e)
      perm[e * RLEAF + bp + (int)__popcll(m & ((1ull << lane) - 1ull))] = gid;
  }
}

// ==================== weight convert+transpose (f32 -> bf16) ====================
__global__ __launch_bounds__(256) void transpose_k(
    const float* __restrict__ s0, const float* __restrict__ s1,
    const float* __restrict__ s2, const float* __restrict__ s3,
    const float* __restrict__ s4,
    u16* __restrict__ d0, u16* __restrict__ d1, u16* __restrict__ d2,
    u16* __restrict__ d3, u16* __restrict__ d4)
{
  int idx = blockIdx.x * 256 + threadIdx.x;
  if (idx < 262144) {                       // nf_W1 [4][256][256] -> [e][o][i]
    int e = idx >> 16, r = idx & 65535, o = r >> 8, i = r & 255;
    d0[idx] = f2b(s0[(e << 16) + (i << 8) + o]);
  } else if (idx < 393216) {                // nf_W2 [4][256][128] -> [4][128][256]
    int t = idx - 262144;
    int e = t >> 15, r = t & 32767, o = r >> 8, i = r & 255;
    d1[t] = f2b(s1[(e << 15) + (i << 7) + o]);
  } else if (idx < 786432) {                // lf_W1 [3][256][512] -> [3][512][256]
    int t = idx - 393216;
    int e = t >> 17, r = t & 131071, o = r >> 8, i = r & 255;
    d2[t] = f2b(s2[(e << 17) + (i << 9) + o]);
  } else if (idx < 983040) {                // lf_W2 [3][512][128] -> [3][128][512]
    int t = idx - 786432;
    int e = t >> 16, r = t & 65535, o = r >> 9, i = r & 511;
    d3[t] = f2b(s3[(e << 16) + (i << 7) + o]);
  } else if (idx < 1239040) {               // ent_emb [2000][128] f32 -> bf16
    int t = idx - 983040;
    d4[t] = f2b(s4[t]);
  }
}

// ==================== fused tree kernel ====================
// Block = 16 trees, 256 threads (4 waves), 67KB dynamic LDS -> 2 blocks/CU.
// Per level: LDS-atomic expert sort -> per-expert 32-row groups ->
// fused relu(x@W1+b1)@W2+b2, h^T = W1t(A)*x^T(B), y^T = W2t(A)*h^T(B).
// Children of row r are src rows 2r, 2r+1.
__global__ __launch_bounds__(256, 2) void tree_k(
    const int* __restrict__ leaf, const int* __restrict__ nf,
    const u16* __restrict__ embB,
    const u16* __restrict__ W1t, const float* __restrict__ b1,
    const u16* __restrict__ W2t, const float* __restrict__ b2,
    u16* __restrict__ roots)
{
  extern __shared__ u16 smem[];
  int* lcnt = (int*)(smem + OFF_C);
  const int tid = threadIdx.x;
  const int w = tid >> 6, lane = tid & 63, lm = lane & 15, lq = lane >> 4;
  const int gt0 = blockIdx.x * TPB;

  #pragma unroll
  for (int lvl = 0; lvl < 4; ++lvl) {
    const int shf = 3 - lvl;
    const int nn = 1 << shf;                 // 8,4,2,1 nodes/tree
    const int R  = TPB << shf;               // 128,64,32,16 rows
    const int io = (lvl == 0) ? 0 : (lvl == 1) ? 8 : (lvl == 2) ? 12 : 14;
    const int so  = (lvl == 2) ? OFF_B : OFF_A;   // src buffer (lvl>=1)
    const int dox = (lvl == 1) ? OFF_B : OFF_A;   // dst buffer (lvl<3)

    // ---- local expert sort (and lvl0 leaf-idx stash) ----
    __syncthreads();
    if (tid < 4) lcnt[tid] = 0;
    __syncthreads();
    if (tid < R) {
      int t = tid >> shf, node = tid & (nn - 1);
      int e = nf[(gt0 + t) * 15 + io + node] & 3;
      int p = atomicAdd(&lcnt[e], 1);
      smem[OFF_L + (e << 7) + p] = (u16)tid;  // row id r == tid
      if (lvl == 0) {
        int ia = leaf[(gt0 + t) * 16 + 2 * node];
        int ib = leaf[(gt0 + t) * 16 + 2 * node + 1];
        ia = ia < 0 ? 0 : (ia > 1999 ? 1999 : ia);   // V_ENT=2000
        ib = ib < 0 ? 0 : (ib > 1999 ? 1999 : ib);
        smem[OFF_LI + 2 * tid]     = (u16)ia;
        smem[OFF_LI + 2 * tid + 1] = (u16)ib;
      }
    }
    __syncthreads();

    // ---- per-expert 32-row groups ----
    for (int e = 0; e < 4; ++e) {
      const int ce = lcnt[e];                // uniform post-barrier
      const u16* __restrict__ Wb  = W1t + e * 65536;   // [256 o][256 i]
      const u16* __restrict__ W2b = W2t + e * 32768;   // [128 o][256 i]
      const float* b1b = b1 + e * 256;
      const float* b2b = b2 + e * 128;

      for (int g = 0; g < ce; g += 32) {
        int rr[2]; bool val[2];
        const u16 *ga[2], *gb[2];
        #pragma unroll
        for (int n = 0; n < 2; ++n) {
          int li = g + n * 16 + lm;
          int lic = li < ce ? li : ce - 1;   // clamp partial tile
          int r = smem[OFF_L + (e << 7) + lic];
          val[n] = li < ce; rr[n] = r;
          if (lvl == 0) {
            ga[n] = embB + (size_t)smem[OFF_LI + 2 * r] * 128;
            gb[n] = embB + (size_t)smem[OFF_LI + 2 * r + 1] * 128;
          }
        }

        // ---- phase 1: h^T = W1t * x^T, +b1, relu -> H ----
        f32x4 acc[4][2];
        #pragma unroll
        for (int m = 0; m < 4; ++m) {
          acc[m][0] = f32x4{0.f, 0.f, 0.f, 0.f};
          acc[m][1] = f32x4{0.f, 0.f, 0.f, 0.f};
        }
        #pragma unroll
        for (int k = 0; k < 8; ++k) {        // K = 256
          const int ko = k * 32 + lq * 8;
          const int cc = k * 4 + lq;         // 16B-chunk of the row PAIR
          v8s bf[2];
          #pragma unroll
          for (int n = 0; n < 2; ++n) {
            if (lvl == 0) {
              bf[n] = *(const v8s*)((ko < 128) ? (ga[n] + ko) : (gb[n] + (ko - 128)));
            } else {
              int r2 = 2 * rr[n] + (cc >= 16 ? 1 : 0);
              bf[n] = *(const v8s*)(smem + so + sw16(r2, cc & 15));
            }
          }
          #pragma unroll
          for (int m = 0; m < 4; ++m) {
            const v8s af = *(const v8s*)(Wb + ((w * 4 + m) * 16 + lm) * 256 + ko);
            acc[m][0] = __builtin_amdgcn_mfma_f32_16x16x32_bf16(af, bf[0], acc[m][0], 0, 0, 0);
            acc[m][1] = __builtin_amdgcn_mfma_f32_16x16x32_bf16(af, bf[1], acc[m][1], 0, 0, 0);
          }
        }
        #pragma unroll
        for (int m = 0; m < 4; ++m) {
          const int f = (w * 4 + m) * 16 + lq * 4;
          const int c = f >> 3, sub = (lq & 1) * 4;
          float bb0 = b1b[f], bb1 = b1b[f + 1], bb2 = b1b[f + 2], bb3 = b1b[f + 3];
          #pragma unroll
          for (int n = 0; n < 2; ++n) {
            union { u16 h[4]; uint2 v; } pk;
            f32x4 a = acc[m][n];
            pk.h[0] = f2b(fmaxf(a.x + bb0, 0.f));
            pk.h[1] = f2b(fmaxf(a.y + bb1, 0.f));
            pk.h[2] = f2b(fmaxf(a.z + bb2, 0.f));
            pk.h[3] = f2b(fmaxf(a.w + bb3, 0.f));
            *(uint2*)&smem[OFF_H + sw32(n * 16 + lm, c) + sub] = pk.v;
          }
        }
        __syncthreads();

        // ---- phase 2: y^T = W2t * h^T ----
        f32x4 a2[2][2];
        #pragma unroll
        for (int m = 0; m < 2; ++m) {
          a2[m][0] = f32x4{0.f, 0.f, 0.f, 0.f};
          a2[m][1] = f32x4{0.f, 0.f, 0.f, 0.f};
        }
        #pragma unroll
        for (int k = 0; k < 8; ++k) {
          const int ko = k * 32 + lq * 8;
          const int cc = k * 4 + lq;
          v8s bf[2];
          #pragma unroll
          for (int n = 0; n < 2; ++n)
            bf[n] = *(const v8s*)(smem + OFF_H + sw32(n * 16 + lm, cc));
          #pragma unroll
          for (int m = 0; m < 2; ++m) {
            const v8s af = *(const v8s*)(W2b + ((w * 2 + m) * 16 + lm) * 256 + ko);
            a2[m][0] = __builtin_amdgcn_mfma_f32_16x16x32_bf16(af, bf[0], a2[m][0], 0, 0, 0);
            a2[m][1] = __builtin_amdgcn_mfma_f32_16x16x32_bf16(af, bf[1], a2[m][1], 0, 0, 0);
          }
        }
        #pragma unroll
        for (int m = 0; m < 2; ++m) {
          const int f = (w * 2 + m) * 16 + lq * 4;
          const int c = f >> 3, sub = (lq & 1) * 4;
          float bb0 = b2b[f], bb1 = b2b[f + 1], bb2 = b2b[f + 2], bb3 = b2b[f + 3];
          #pragma unroll
          for (int n = 0; n < 2; ++n) {
            if (val[n]) {
              union { u16 h[4]; uint2 v; } pk;
              f32x4 a = a2[m][n];
              pk.h[0] = f2b(a.x + bb0);
              pk.h[1] = f2b(a.y + bb1);
              pk.h[2] = f2b(a.z + bb2);
              pk.h[3] = f2b(a.w + bb3);
              if (lvl < 3)
                *(uint2*)&smem[dox + sw16(rr[n], c) + sub] = pk.v;
              else
                *(uint2*)(roots + (size_t)(gt0 + rr[n]) * 128 + f) = pk.v;
            }
          }
        }
        __syncthreads();                    // H reused by next group
      }
    }
  }
}

// ==================== leaf expert MLP (global roots -> stmt) ====================
__global__ __launch_bounds__(256, 2) void leafmlp_k(
    const u16* __restrict__ src,
    const int* __restrict__ perm, const int* __restrict__ cnt,
    const u16* __restrict__ W1t, const float* __restrict__ b1,
    const u16* __restrict__ W2t, const float* __restrict__ b2,
    u16* __restrict__ dst)
{
  constexpr int HID = 512, MR = 32;
  constexpr int HSTR = HID + 8;
  constexpr int NT = MR / 16;         // 2
  constexpr int MT1 = HID / 64;       // 8
  __shared__ __align__(16) u16 hs[MR * HSTR];

  int bin = -1, tile = 0, cb = 0;
  {
    int rem = blockIdx.x;
    #pragma unroll
    for (int e = 0; e < 3; ++e) {
      int ce = cnt[e];
      int tt = (ce + MR - 1) / MR;
      if (bin < 0) {
        if (rem < tt) { bin = e; tile = rem; cb = ce; }
        else rem -= tt;
      }
    }
  }
  if (bin < 0) return;
  const int rbase = tile * MR;
  const int tid = threadIdx.x;
  const int w  = tid >> 6;
  const int lane = tid & 63;
  const int lm = lane & 15;
  const int lq = lane >> 4;

  const u16* rpa[NT]; const u16* rpb[NT]; int rowid[NT];
  #pragma unroll
  for (int n = 0; n < NT; ++n) {
    int rl = rbase + n * 16 + lm;
    int rlc = rl < cb ? rl : (cb - 1);
    int rc = perm[(size_t)bin * RLEAF + rlc];
    rc = rc < 0 ? 0 : (rc >= RLEAF ? RLEAF - 1 : rc);
    rowid[n] = (rl < cb) ? rc : -1;
    int bq = rc / 9, g = rc - bq * 9;
    rpa[n] = src + ((size_t)bq * 34 + 16 + 2 * g) * 128;
    rpb[n] = rpa[n] + 128;
  }

  const u16* __restrict__ Wb = W1t + (size_t)bin * HID * 256;
  f32x4 acc[MT1][NT];
  #pragma unroll
  for (int m = 0; m < MT1; ++m)
    #pragma unroll
    for (int n = 0; n < NT; ++n)
      acc[m][n] = f32x4{0.f, 0.f, 0.f, 0.f};

  #pragma unroll
  for (int k = 0; k < 8; ++k) {
    const int ko = k * 32 + lq * 8;
    v8s bfr[NT];
    #pragma unroll
    for (int n = 0; n < NT; ++n) {
      const u16* p = (ko < 128) ? (rpa[n] + ko) : (rpb[n] + (ko - 128));
      bfr[n] = *(const v8s*)p;
    }
    #pragma unroll
    for (int m = 0; m < MT1; ++m) {
      const v8s af = *(const v8s*)(Wb + (size_t)((w * MT1 + m) * 16 + lm) * 256 + ko);
      #pragma unroll
      for (int n = 0; n < NT; ++n)
        acc[m][n] = __builtin_amdgcn_mfma_f32_16x16x32_bf16(af, bfr[n], acc[m][n], 0, 0, 0);
    }
  }
  const float* b1b = b1 + bin * HID;
  #pragma unroll
  for (int m = 0; m < MT1; ++m) {
    const int f = (w * MT1 + m) * 16 + lq * 4;
    float bb0 = b1b[f], bb1 = b1b[f + 1], bb2 = b1b[f + 2], bb3 = b1b[f + 3];
    #pragma unroll
    for (int n = 0; n < NT; ++n) {
      union { u16 h[4]; uint2 v; } pk;
      f32x4 a = acc[m][n];
      pk.h[0] = f2b(fmaxf(a.x + bb0, 0.f));
      pk.h[1] = f2b(fmaxf(a.y + bb1, 0.f));
      pk.h[2] = f2b(fmaxf(a.z + bb2, 0.f));
      pk.h[3] = f2b(fmaxf(a.w + bb3, 0.f));
      *(uint2*)&hs[(n * 16 + lm) * HSTR + f] = pk.v;
    }
  }
  __syncthreads();

  const u16* __restrict__ W2b = W2t + (size_t)bin * 128 * HID;
  f32x4 acc2[2][NT];
  #pragma unroll
  for (int m = 0; m < 2; ++m)
    #pragma unroll
    for (int n = 0; n < NT; ++n)
      acc2[m][n] = f32x4{0.f, 0.f, 0.f, 0.f};

  #pragma unroll 4
  for (int k = 0; k < HID / 32; ++k) {
    const int ko = k * 32 + lq * 8;
    v8s bfr[NT];
    #pragma unroll
    for (int n = 0; n < NT; ++n)
      bfr[n] = *(const v8s*)&hs[(n * 16 + lm) * HSTR + ko];
    #pragma unroll
    for (int m = 0; m < 2; ++m) {
      const v8s af = *(const v8s*)(W2b + (size_t)((w * 2 + m) * 16 + lm) * HID + ko);
      #pragma unroll
      for (int n = 0; n < NT; ++n)
        acc2[m][n] = __builtin_amdgcn_mfma_f32_16x16x32_bf16(af, bfr[n], acc2[m][n], 0, 0, 0);
    }
  }
  const float* b2b = b2 + bin * 128;
  #pragma unroll
  for (int m = 0; m < 2; ++m) {
    const int f = (w * 2 + m) * 16 + lq * 4;
    float bb0 = b2b[f], bb1 = b2b[f + 1], bb2 = b2b[f + 2], bb3 = b2b[f + 3];
    #pragma unroll
    for (int n = 0; n < NT; ++n) {
      if (rowid[n] >= 0) {
        union { u16 h[4]; uint2 v; } pk;
        f32x4 a = acc2[m][n];
        pk.h[0] = f2b(a.x + bb0);
        pk.h[1] = f2b(a.y + bb1);
        pk.h[2] = f2b(a.z + bb2);
        pk.h[3] = f2b(a.w + bb3);
        *(uint2*)(dst + (size_t)rowid[n] * 128 + f) = pk.v;
      }
    }
  }
}

// ==================== attention + concat (fp32) ====================
__global__ __launch_bounds__(128) void attn_k(
    const u16* __restrict__ stmt, const u16* __restrict__ roots,
    const float* __restrict__ themb, const int* __restrict__ thidx,
    const float* __restrict__ wHe, const float* __restrict__ bHe,
    const float* __restrict__ wHg, const float* __restrict__ bHg,
    const float* __restrict__ wHt, const float* __restrict__ bHt,
    float* __restrict__ out)
{
  const int b = blockIdx.x, t = threadIdx.x;   // 128 threads
  __shared__ float obj_s[128], q_s[128], keys_s[16 * 132], a_s[16];

  const float obj = b2f(stmt[((size_t)b * 9 + 8) * 128 + t]);
  obj_s[t] = obj;
  out[(size_t)b * 512 + t] = obj;              // obj passthrough
  __syncthreads();

  for (int a = 0; a < 3; ++a) {               // 0: gt_ctx, 1: ent_ctx, 2: th_ctx
    int cntk;
    const float *Wt, *bv;
    if (a == 0) {
      cntk = 8; Wt = wHg; bv = bHg;
      for (int j = 0; j < 8; ++j)
        keys_s[j * 132 + t] = b2f(stmt[((size_t)b * 9 + j) * 128 + t]);
    } else if (a == 1) {
      cntk = 16; Wt = wHe; bv = bHe;
      for (int j = 0; j < 16; ++j)
        keys_s[j * 132 + t] = b2f(roots[((size_t)b * 34 + j) * 128 + t]);
    } else {
      cntk = 8; Wt = wHt; bv = bHt;           // TH_MAX = 8
      for (int j = 0; j < 8; ++j) {
        int ti = thidx[b * 8 + j] & 31;        // V_TH = 32
        keys_s[j * 132 + t] = themb[(size_t)ti * 128 + t];
      }
    }
    float qa = bv[t];
    for (int k = 0; k < 128; ++k) qa += obj_s[k] * Wt[k * 128 + t];
    q_s[t] = (qa == qa) ? qa : 0.f;
    __syncthreads();
    if (t < cntk) {
      float sc = 0.f;
      for (int k = 0; k < 128; ++k) sc += keys_s[t * 132 + k] * q_s[k];
      a_s[t] = (sc == sc) ? sc : 0.f;
    }
    __syncthreads();
    if (t == 0) {
      float mx = a_s[0];
      for (int j = 1; j < cntk; ++j) mx = fmaxf(mx, a_s[j]);
      float sm = 0.f;
      for (int j = 0; j < cntk; ++j) { float e = expf(a_s[j] - mx); a_s[j] = e; sm += e; }
      float inv = 1.f / sm;
      for (int j = 0; j < cntk; ++j) a_s[j] *= inv;
    }
    __syncthreads();
    float c = 0.f;
    for (int j = 0; j < cntk; ++j) c += a_s[j] * keys_s[j * 132 + t];
    out[(size_t)b * 512 + 128 * (a + 1) + t] = c;
    __syncthreads();
  }
}

// ==================== launch ====================
extern "C" void kernel_launch(void* const* d_in, const int* in_sizes, int n_in,
                              void* d_out, int out_size, void* d_ws, size_t ws_size,
                              hipStream_t stream)
{
  const int*   leaf_idx = (const int*)d_in[0];
  const int*   nf_ids   = (const int*)d_in[1];
  const int*   lf_ids   = (const int*)d_in[2];
  const int*   th_idx   = (const int*)d_in[3];
  const float* ent_emb  = (const float*)d_in[4];
  const float* th_emb   = (const float*)d_in[5];
  const float* nf_W1 = (const float*)d_in[6];
  const float* nf_b1 = (const float*)d_in[7];
  const float* nf_W2 = (const float*)d_in[8];
  const float* nf_b2 = (const float*)d_in[9];
  const float* lf_W1 = (const float*)d_in[10];
  const float* lf_b1 = (const float*)d_in[11];
  const float* lf_W2 = (const float*)d_in[12];
  const float* lf_b2 = (const float*)d_in[13];
  const float* he_W = (const float*)d_in[14];
  const float* he_b = (const float*)d_in[15];
  const float* hg_W = (const float*)d_in[16];
  const float* hg_b = (const float*)d_in[17];
  const float* ht_W = (const float*)d_in[18];
  const float* ht_b = (const float*)d_in[19];

  char* ws = (char*)d_ws;
  size_t off = 0;
  auto take = [&](size_t bytes) -> char* {
    char* p = ws + off;
    off = (off + bytes + 255) & ~(size_t)255;
    return p;
  };
  int* leafcnt  = (int*)take(256);
  int* leafperm = (int*)take((size_t)3 * RLEAF * 4);      // 110.6 KB
  u16* wN1  = (u16*)take((size_t)4 * 256 * 256 * 2);      // 512 KB
  u16* wN2  = (u16*)take((size_t)4 * 128 * 256 * 2);      // 256 KB
  u16* wL1  = (u16*)take((size_t)3 * 512 * 256 * 2);      // 786 KB
  u16* wL2  = (u16*)take((size_t)3 * 128 * 512 * 2);      // 393 KB
  u16* embB = (u16*)take((size_t)2000 * 128 * 2);         // 512 KB
  u16* roots = (u16*)take((size_t)NTREE * 128 * 2);       // 8.91 MB
  u16* stmt  = (u16*)take((size_t)RLEAF * 128 * 2);       // 2.36 MB
  // total ~13.9 MB

  hipMemsetAsync(leafcnt, 0, 32, stream);
  transpose_k<<<4840, 256, 0, stream>>>(nf_W1, nf_W2, lf_W1, lf_W2, ent_emb,
                                        wN1, wN2, wL1, wL2, embB);
  leaf_perm_k<<<36, 256, 0, stream>>>(lf_ids, leafcnt, leafperm);

  tree_k<<<NTREE / TPB, 256, SMEM_U16 * 2, stream>>>(
      leaf_idx, nf_ids, embB, wN1, nf_b1, wN2, nf_b2, roots);

  leafmlp_k<<<RLEAF / 32 + 3, 256, 0, stream>>>(
      roots, leafperm, leafcnt, wL1, lf_b1, wL2, lf_b2, stmt);

  attn_k<<<1024, 128, 0, stream>>>(stmt, roots, th_emb, th_idx,
                                   he_W, he_b, hg_W, hg_b, ht_W, ht_b,
                                   (float*)d_out);
}

// Round 8
// 1237.820 us; speedup vs baseline: 1.6471x; 1.6471x over previous
//
#include <hip/hip_runtime.h>
#include <math.h>

// RecursiveAttentiveEncoder — fused-tree MFMA, R8.
// R7 post-mortem: rewrite caused register SPILL (VGPR 236->128, 3.2 GB HBM
// scratch traffic, MfmaUtil 5%). R8 reverts to the verified R6 structure and
// changes ONLY the occupancy lever: TPB 32->16, MR 64->32 => 70.7 KB LDS =>
// 2 blocks/CU (2 waves/SIMD) for 2x latency hiding. Registers shrink (acc
// tiles halved), no launch-bounds tightening, same stride-136 LDS rows
// (conflicts measured at ~4% of runtime — acceptable). Leaf-idx gathers
// hoisted into the sort phase (verified in R7).

typedef unsigned short u16;
typedef unsigned int   u32;
typedef unsigned long long u64;
typedef __attribute__((ext_vector_type(8))) short v8s;   // 8 bf16 (4 VGPRs)
typedef __attribute__((ext_vector_type(4))) float f32x4; // MFMA acc

__device__ __forceinline__ float b2f(u16 u) { return __uint_as_float(((u32)u) << 16); }
__device__ __forceinline__ u16 f2b(float f) {
  f = (f == f) ? f : 0.f;                    // NaN squash (hygiene)
  u32 x = __float_as_uint(f);
  u32 r = x + 0x7fffu + ((x >> 16) & 1u);
  return (u16)(r >> 16);
}

#define NTREE 34816   // B*T_TREES = 1024*34
#define RLEAF 9216    // B*(GT_MAX+1)
#define TPB   16      // trees per block in tree_k

// tree_k LDS layout, u16 units (total 35344 u16 = 70688 B -> 2 blocks/CU)
#define OFF_A  0      // 16 trees * 8 rows * 136 = 17408  (lvl0 out, lvl2 out)
#define OFF_B  17408  // 16 * 4 * 136 = 8704              (lvl1 out)
#define OFF_H  26112  // 32 rows * 264 = 8448             (phase-1 h scratch)
#define OFF_L  34560  // bin lists: 4 * 128 = 512         (u16 row ids)
#define OFF_LI 35072  // lvl0 leaf-idx pairs: 128*2 = 256
#define OFF_C  35328  // 4 int counters (16 u16)
#define SMEM_U16 35344

// ==================== leaf-stage expert sort ====================
__global__ __launch_bounds__(256) void leaf_perm_k(
    const int* __restrict__ lf, int* __restrict__ cnt, int* __restrict__ perm)
{
  const int gid = blockIdx.x * 256 + threadIdx.x;   // 36*256 = 9216 exact
  const int id = lf[gid];
  const int lane = threadIdx.x & 63;
  for (int e = 0; e < 3; ++e) {
    u64 m = __ballot(id == e);
    if (!m) continue;
    int leader = __builtin_ctzll(m);
    int bp = 0;
    if (lane == leader) bp = atomicAdd(&cnt[e], (int)__popcll(m));
    bp = __shfl(bp, leader);
    if (id == e)
      perm[e * RLEAF + bp + (int)__popcll(m & ((1ull << lane) - 1ull))] = gid;
  }
}

// ==================== weight convert+transpose (f32 -> bf16) ====================
__global__ __launch_bounds__(256) void transpose_k(
    const float* __restrict__ s0, const float* __restrict__ s1,
    const float* __restrict__ s2, const float* __restrict__ s3,
    const float* __restrict__ s4,
    u16* __restrict__ d0, u16* __restrict__ d1, u16* __restrict__ d2,
    u16* __restrict__ d3, u16* __restrict__ d4)
{
  int idx = blockIdx.x * 256 + threadIdx.x;
  if (idx < 262144) {                       // nf_W1 [4][256][256] -> [e][o][i]
    int e = idx >> 16, r = idx & 65535, o = r >> 8, i = r & 255;
    d0[idx] = f2b(s0[(e << 16) + (i << 8) + o]);
  } else if (idx < 393216) {                // nf_W2 [4][256][128] -> [4][128][256]
    int t = idx - 262144;
    int e = t >> 15, r = t & 32767, o = r >> 8, i = r & 255;
    d1[t] = f2b(s1[(e << 15) + (i << 7) + o]);
  } else if (idx < 786432) {                // lf_W1 [3][256][512] -> [3][512][256]
    int t = idx - 393216;
    int e = t >> 17, r = t & 131071, o = r >> 8, i = r & 255;
    d2[t] = f2b(s2[(e << 17) + (i << 9) + o]);
  } else if (idx < 983040) {                // lf_W2 [3][512][128] -> [3][128][512]
    int t = idx - 786432;
    int e = t >> 16, r = t & 65535, o = r >> 9, i = r & 511;
    d3[t] = f2b(s3[(e << 16) + (i << 7) + o]);
  } else if (idx < 1239040) {               // ent_emb [2000][128] f32 -> bf16
    int t = idx - 983040;
    d4[t] = f2b(s4[t]);
  }
}

// ==================== fused tree kernel ====================
// Block = 16 trees, 256 threads (4 waves), 70.7KB dynamic LDS -> 2 blocks/CU.
// Per level: LDS-atomic expert sort -> per-expert 32-row groups ->
// fused relu(x@W1+b1)@W2+b2, h^T = W1t(A)*x^T(B), y^T = W2t(A)*h^T(B).
// Children of row r are src rows 2r, 2r+1.
__global__ __launch_bounds__(256, 1) void tree_k(
    const int* __restrict__ leaf, const int* __restrict__ nf,
    const u16* __restrict__ embB,
    const u16* __restrict__ W1t, const float* __restrict__ b1,
    const u16* __restrict__ W2t, const float* __restrict__ b2,
    u16* __restrict__ roots)
{
  extern __shared__ u16 smem[];
  int* lcnt = (int*)(smem + OFF_C);
  const int tid = threadIdx.x;
  const int w = tid >> 6, lane = tid & 63, lm = lane & 15, lq = lane >> 4;
  const int gt0 = blockIdx.x * TPB;

  const int nArr[4]  = {8, 4, 2, 1};
  const int ioArr[4] = {0, 8, 12, 14};
  const int soArr[4] = {0, OFF_A, OFF_B, OFF_A};
  const int doArr[4] = {OFF_A, OFF_B, OFF_A, 0};

  #pragma unroll
  for (int lvl = 0; lvl < 4; ++lvl) {
    const int nn = nArr[lvl];
    const int R  = TPB * nn;                 // 128,64,32,16 rows
    const int io = ioArr[lvl];
    const int so = soArr[lvl];
    const int dox = doArr[lvl];

    // ---- local expert sort (and lvl0 leaf-idx stash) ----
    __syncthreads();                        // prior level's reads complete
    if (tid < 4) lcnt[tid] = 0;
    __syncthreads();
    if (tid < R) {
      int t = tid / nn, node = tid - t * nn;
      int e = nf[(gt0 + t) * 15 + io + node] & 3;
      int p = atomicAdd(&lcnt[e], 1);
      smem[OFF_L + (e << 7) + p] = (u16)tid;  // row id r == tid
      if (lvl == 0) {
        int ia = leaf[(gt0 + t) * 16 + 2 * node];
        int ib = leaf[(gt0 + t) * 16 + 2 * node + 1];
        ia = ia < 0 ? 0 : (ia > 1999 ? 1999 : ia);   // V_ENT=2000
        ib = ib < 0 ? 0 : (ib > 1999 ? 1999 : ib);
        smem[OFF_LI + 2 * tid]     = (u16)ia;
        smem[OFF_LI + 2 * tid + 1] = (u16)ib;
      }
    }
    __syncthreads();

    // ---- per-expert 32-row groups ----
    for (int e = 0; e < 4; ++e) {
      const int ce = lcnt[e];               // uniform (post-barrier)
      const u16* __restrict__ Wb  = W1t + e * 65536;   // [256 o][256 i]
      const u16* __restrict__ W2b = W2t + e * 32768;   // [128 o][256 i]
      const float* b1b = b1 + e * 256;
      const float* b2b = b2 + e * 128;

      for (int g = 0; g < ce; g += 32) {
        int rloc[2]; bool val[2];
        const u16 *gpa[2], *gpb[2];
        int oa[2], ob[2];
        #pragma unroll
        for (int n = 0; n < 2; ++n) {
          int li = g + n * 16 + lm;
          int lic = li < ce ? li : ce - 1;   // clamp partial tile
          int r = smem[OFF_L + (e << 7) + lic];
          val[n] = li < ce;
          rloc[n] = r;
          if (lvl == 0) {
            gpa[n] = embB + (size_t)smem[OFF_LI + 2 * r] * 128;
            gpb[n] = embB + (size_t)smem[OFF_LI + 2 * r + 1] * 128;
          } else {
            oa[n] = so + (2 * r) * 136;      // children rows 2r, 2r+1
            ob[n] = so + (2 * r + 1) * 136;
          }
        }

        // ---- phase 1: h^T = W1t * x^T, +b1, relu -> OFF_H ----
        f32x4 acc[4][2];
        #pragma unroll
        for (int m = 0; m < 4; ++m) {
          acc[m][0] = f32x4{0.f, 0.f, 0.f, 0.f};
          acc[m][1] = f32x4{0.f, 0.f, 0.f, 0.f};
        }

        #pragma unroll
        for (int k = 0; k < 8; ++k) {        // K = 256
          const int ko = k * 32 + lq * 8;
          v8s bfr[2];
          if (lvl == 0) {
            #pragma unroll
            for (int n = 0; n < 2; ++n)
              bfr[n] = *(const v8s*)((ko < 128) ? (gpa[n] + ko) : (gpb[n] + (ko - 128)));
          } else {
            #pragma unroll
            for (int n = 0; n < 2; ++n)
              bfr[n] = *(const v8s*)(smem + ((ko < 128) ? (oa[n] + ko) : (ob[n] + (ko - 128))));
          }
          #pragma unroll
          for (int m = 0; m < 4; ++m) {
            const v8s af = *(const v8s*)(Wb + (size_t)((w * 4 + m) * 16 + lm) * 256 + ko);
            acc[m][0] = __builtin_amdgcn_mfma_f32_16x16x32_bf16(af, bfr[0], acc[m][0], 0, 0, 0);
            acc[m][1] = __builtin_amdgcn_mfma_f32_16x16x32_bf16(af, bfr[1], acc[m][1], 0, 0, 0);
          }
        }
        #pragma unroll
        for (int m = 0; m < 4; ++m) {
          const int f = (w * 4 + m) * 16 + lq * 4;
          float bb0 = b1b[f], bb1 = b1b[f + 1], bb2 = b1b[f + 2], bb3 = b1b[f + 3];
          #pragma unroll
          for (int n = 0; n < 2; ++n) {
            union { u16 h[4]; uint2 v; } pk;
            f32x4 a = acc[m][n];
            pk.h[0] = f2b(fmaxf(a.x + bb0, 0.f));
            pk.h[1] = f2b(fmaxf(a.y + bb1, 0.f));
            pk.h[2] = f2b(fmaxf(a.z + bb2, 0.f));
            pk.h[3] = f2b(fmaxf(a.w + bb3, 0.f));
            *(uint2*)&smem[OFF_H + (n * 16 + lm) * 264 + f] = pk.v;
          }
        }
        __syncthreads();

        // ---- phase 2: y^T = W2t * h^T ----
        f32x4 a2[2][2];
        #pragma unroll
        for (int m = 0; m < 2; ++m) {
          a2[m][0] = f32x4{0.f, 0.f, 0.f, 0.f};
          a2[m][1] = f32x4{0.f, 0.f, 0.f, 0.f};
        }
        #pragma unroll
        for (int k = 0; k < 8; ++k) {
          const int ko = k * 32 + lq * 8;
          v8s bfr[2];
          #pragma unroll
          for (int n = 0; n < 2; ++n)
            bfr[n] = *(const v8s*)(smem + OFF_H + (n * 16 + lm) * 264 + ko);
          #pragma unroll
          for (int m = 0; m < 2; ++m) {
            const v8s af = *(const v8s*)(W2b + (size_t)((w * 2 + m) * 16 + lm) * 256 + ko);
            a2[m][0] = __builtin_amdgcn_mfma_f32_16x16x32_bf16(af, bfr[0], a2[m][0], 0, 0, 0);
            a2[m][1] = __builtin_amdgcn_mfma_f32_16x16x32_bf16(af, bfr[1], a2[m][1], 0, 0, 0);
          }
        }
        #pragma unroll
        for (int m = 0; m < 2; ++m) {
          const int f = (w * 2 + m) * 16 + lq * 4;
          float bb0 = b2b[f], bb1 = b2b[f + 1], bb2 = b2b[f + 2], bb3 = b2b[f + 3];
          #pragma unroll
          for (int n = 0; n < 2; ++n) {
            if (val[n]) {
              union { u16 h[4]; uint2 v; } pk;
              f32x4 a = a2[m][n];
              pk.h[0] = f2b(a.x + bb0);
              pk.h[1] = f2b(a.y + bb1);
              pk.h[2] = f2b(a.z + bb2);
              pk.h[3] = f2b(a.w + bb3);
              if (lvl < 3)
                *(uint2*)&smem[dox + rloc[n] * 136 + f] = pk.v;
              else
                *(uint2*)(roots + (size_t)(gt0 + rloc[n]) * 128 + f) = pk.v;
            }
          }
        }
        __syncthreads();                    // H reused by next group
      }
    }
  }
}

// ==================== leaf expert MLP (global roots -> stmt) ====================
__global__ __launch_bounds__(256, 2) void leafmlp_k(
    const u16* __restrict__ src,
    const int* __restrict__ perm, const int* __restrict__ cnt,
    const u16* __restrict__ W1t, const float* __restrict__ b1,
    const u16* __restrict__ W2t, const float* __restrict__ b2,
    u16* __restrict__ dst)
{
  constexpr int HID = 512, MR = 32;
  constexpr int HSTR = HID + 8;
  constexpr int NT = MR / 16;         // 2
  constexpr int MT1 = HID / 64;       // 8
  __shared__ __align__(16) u16 hs[MR * HSTR];

  int bin = -1, tile = 0, cb = 0;
  {
    int rem = blockIdx.x;
    #pragma unroll
    for (int e = 0; e < 3; ++e) {
      int ce = cnt[e];
      int tt = (ce + MR - 1) / MR;
      if (bin < 0) {
        if (rem < tt) { bin = e; tile = rem; cb = ce; }
        else rem -= tt;
      }
    }
  }
  if (bin < 0) return;
  const int rbase = tile * MR;
  const int tid = threadIdx.x;
  const int w  = tid >> 6;
  const int lane = tid & 63;
  const int lm = lane & 15;
  const int lq = lane >> 4;

  const u16* rpa[NT]; const u16* rpb[NT]; int rowid[NT];
  #pragma unroll
  for (int n = 0; n < NT; ++n) {
    int rl = rbase + n * 16 + lm;
    int rlc = rl < cb ? rl : (cb - 1);
    int rc = perm[(size_t)bin * RLEAF + rlc];
    rc = rc < 0 ? 0 : (rc >= RLEAF ? RLEAF - 1 : rc);
    rowid[n] = (rl < cb) ? rc : -1;
    int bq = rc / 9, g = rc - bq * 9;
    rpa[n] = src + ((size_t)bq * 34 + 16 + 2 * g) * 128;
    rpb[n] = rpa[n] + 128;
  }

  const u16* __restrict__ Wb = W1t + (size_t)bin * HID * 256;
  f32x4 acc[MT1][NT];
  #pragma unroll
  for (int m = 0; m < MT1; ++m)
    #pragma unroll
    for (int n = 0; n < NT; ++n)
      acc[m][n] = f32x4{0.f, 0.f, 0.f, 0.f};

  #pragma unroll
  for (int k = 0; k < 8; ++k) {
    const int ko = k * 32 + lq * 8;
    v8s bfr[NT];
    #pragma unroll
    for (int n = 0; n < NT; ++n) {
      const u16* p = (ko < 128) ? (rpa[n] + ko) : (rpb[n] + (ko - 128));
      bfr[n] = *(const v8s*)p;
    }
    #pragma unroll
    for (int m = 0; m < MT1; ++m) {
      const v8s af = *(const v8s*)(Wb + (size_t)((w * MT1 + m) * 16 + lm) * 256 + ko);
      #pragma unroll
      for (int n = 0; n < NT; ++n)
        acc[m][n] = __builtin_amdgcn_mfma_f32_16x16x32_bf16(af, bfr[n], acc[m][n], 0, 0, 0);
    }
  }
  const float* b1b = b1 + bin * HID;
  #pragma unroll
  for (int m = 0; m < MT1; ++m) {
    const int f = (w * MT1 + m) * 16 + lq * 4;
    float bb0 = b1b[f], bb1 = b1b[f + 1], bb2 = b1b[f + 2], bb3 = b1b[f + 3];
    #pragma unroll
    for (int n = 0; n < NT; ++n) {
      union { u16 h[4]; uint2 v; } pk;
      f32x4 a = acc[m][n];
      pk.h[0] = f2b(fmaxf(a.x + bb0, 0.f));
      pk.h[1] = f2b(fmaxf(a.y + bb1, 0.f));
      pk.h[2] = f2b(fmaxf(a.z + bb2, 0.f));
      pk.h[3] = f2b(fmaxf(a.w + bb3, 0.f));
      *(uint2*)&hs[(n * 16 + lm) * HSTR + f] = pk.v;
    }
  }
  __syncthreads();

  const u16* __restrict__ W2b = W2t + (size_t)bin * 128 * HID;
  f32x4 acc2[2][NT];
  #pragma unroll
  for (int m = 0; m < 2; ++m)
    #pragma unroll
    for (int n = 0; n < NT; ++n)
      acc2[m][n] = f32x4{0.f, 0.f, 0.f, 0.f};

  #pragma unroll 4
  for (int k = 0; k < HID / 32; ++k) {
    const int ko = k * 32 + lq * 8;
    v8s bfr[NT];
    #pragma unroll
    for (int n = 0; n < NT; ++n)
      bfr[n] = *(const v8s*)&hs[(n * 16 + lm) * HSTR + ko];
    #pragma unroll
    for (int m = 0; m < 2; ++m) {
      const v8s af = *(const v8s*)(W2b + (size_t)((w * 2 + m) * 16 + lm) * HID + ko);
      #pragma unroll
      for (int n = 0; n < NT; ++n)
        acc2[m][n] = __builtin_amdgcn_mfma_f32_16x16x32_bf16(af, bfr[n], acc2[m][n], 0, 0, 0);
    }
  }
  const float* b2b = b2 + bin * 128;
  #pragma unroll
  for (int m = 0; m < 2; ++m) {
    const int f = (w * 2 + m) * 16 + lq * 4;
    float bb0 = b2b[f], bb1 = b2b[f + 1], bb2 = b2b[f + 2], bb3 = b2b[f + 3];
    #pragma unroll
    for (int n = 0; n < NT; ++n) {
      if (rowid[n] >= 0) {
        union { u16 h[4]; uint2 v; } pk;
        f32x4 a = acc2[m][n];
        pk.h[0] = f2b(a.x + bb0);
        pk.h[1] = f2b(a.y + bb1);
        pk.h[2] = f2b(a.z + bb2);
        pk.h[3] = f2b(a.w + bb3);
        *(uint2*)(dst + (size_t)rowid[n] * 128 + f) = pk.v;
      }
    }
  }
}

// ==================== attention + concat (fp32) ====================
__global__ __launch_bounds__(128) void attn_k(
    const u16* __restrict__ stmt, const u16* __restrict__ roots,
    const float* __restrict__ themb, const int* __restrict__ thidx,
    const float* __restrict__ wHe, const float* __restrict__ bHe,
    const float* __restrict__ wHg, const float* __restrict__ bHg,
    const float* __restrict__ wHt, const float* __restrict__ bHt,
    float* __restrict__ out)
{
  const int b = blockIdx.x, t = threadIdx.x;   // 128 threads
  __shared__ float obj_s[128], q_s[128], keys_s[16 * 132], a_s[16];

  const float obj = b2f(stmt[((size_t)b * 9 + 8) * 128 + t]);
  obj_s[t] = obj;
  out[(size_t)b * 512 + t] = obj;              // obj passthrough
  __syncthreads();

  for (int a = 0; a < 3; ++a) {               // 0: gt_ctx, 1: ent_ctx, 2: th_ctx
    int cntk;
    const float *Wt, *bv;
    if (a == 0) {
      cntk = 8; Wt = wHg; bv = bHg;
      for (int j = 0; j < 8; ++j)
        keys_s[j * 132 + t] = b2f(stmt[((size_t)b * 9 + j) * 128 + t]);
    } else if (a == 1) {
      cntk = 16; Wt = wHe; bv = bHe;
      for (int j = 0; j < 16; ++j)
        keys_s[j * 132 + t] = b2f(roots[((size_t)b * 34 + j) * 128 + t]);
    } else {
      cntk = 8; Wt = wHt; bv = bHt;           // TH_MAX = 8
      for (int j = 0; j < 8; ++j) {
        int ti = thidx[b * 8 + j] & 31;        // V_TH = 32
        keys_s[j * 132 + t] = themb[(size_t)ti * 128 + t];
      }
    }
    float qa = bv[t];
    for (int k = 0; k < 128; ++k) qa += obj_s[k] * Wt[k * 128 + t];
    q_s[t] = (qa == qa) ? qa : 0.f;
    __syncthreads();
    if (t < cntk) {
      float sc = 0.f;
      for (int k = 0; k < 128; ++k) sc += keys_s[t * 132 + k] * q_s[k];
      a_s[t] = (sc == sc) ? sc : 0.f;
    }
    __syncthreads();
    if (t == 0) {
      float mx = a_s[0];
      for (int j = 1; j < cntk; ++j) mx = fmaxf(mx, a_s[j]);
      float sm = 0.f;
      for (int j = 0; j < cntk; ++j) { float e = expf(a_s[j] - mx); a_s[j] = e; sm += e; }
      float inv = 1.f / sm;
      for (int j = 0; j < cntk; ++j) a_s[j] *= inv;
    }
    __syncthreads();
    float c = 0.f;
    for (int j = 0; j < cntk; ++j) c += a_s[j] * keys_s[j * 132 + t];
    out[(size_t)b * 512 + 128 * (a + 1) + t] = c;
    __syncthreads();
  }
}

// ==================== launch ====================
extern "C" void kernel_launch(void* const* d_in, const int* in_sizes, int n_in,
                              void* d_out, int out_size, void* d_ws, size_t ws_size,
                              hipStream_t stream)
{
  const int*   leaf_idx = (const int*)d_in[0];
  const int*   nf_ids   = (const int*)d_in[1];
  const int*   lf_ids   = (const int*)d_in[2];
  const int*   th_idx   = (const int*)d_in[3];
  const float* ent_emb  = (const float*)d_in[4];
  const float* th_emb   = (const float*)d_in[5];
  const float* nf_W1 = (const float*)d_in[6];
  const float* nf_b1 = (const float*)d_in[7];
  const float* nf_W2 = (const float*)d_in[8];
  const float* nf_b2 = (const float*)d_in[9];
  const float* lf_W1 = (const float*)d_in[10];
  const float* lf_b1 = (const float*)d_in[11];
  const float* lf_W2 = (const float*)d_in[12];
  const float* lf_b2 = (const float*)d_in[13];
  const float* he_W = (const float*)d_in[14];
  const float* he_b = (const float*)d_in[15];
  const float* hg_W = (const float*)d_in[16];
  const float* hg_b = (const float*)d_in[17];
  const float* ht_W = (const float*)d_in[18];
  const float* ht_b = (const float*)d_in[19];

  char* ws = (char*)d_ws;
  size_t off = 0;
  auto take = [&](size_t bytes) -> char* {
    char* p = ws + off;
    off = (off + bytes + 255) & ~(size_t)255;
    return p;
  };
  int* leafcnt  = (int*)take(256);
  int* leafperm = (int*)take((size_t)3 * RLEAF * 4);      // 110.6 KB
  u16* wN1  = (u16*)take((size_t)4 * 256 * 256 * 2);      // 512 KB
  u16* wN2  = (u16*)take((size_t)4 * 128 * 256 * 2);      // 256 KB
  u16* wL1  = (u16*)take((size_t)3 * 512 * 256 * 2);      // 786 KB
  u16* wL2  = (u16*)take((size_t)3 * 128 * 512 * 2);      // 393 KB
  u16* embB = (u16*)take((size_t)2000 * 128 * 2);         // 512 KB
  u16* roots = (u16*)take((size_t)NTREE * 128 * 2);       // 8.91 MB
  u16* stmt  = (u16*)take((size_t)RLEAF * 128 * 2);       // 2.36 MB
  // total ~13.9 MB

  hipMemsetAsync(leafcnt, 0, 32, stream);
  transpose_k<<<4840, 256, 0, stream>>>(nf_W1, nf_W2, lf_W1, lf_W2, ent_emb,
                                        wN1, wN2, wL1, wL2, embB);
  leaf_perm_k<<<36, 256, 0, stream>>>(lf_ids, leafcnt, leafperm);

  tree_k<<<NTREE / TPB, 256, SMEM_U16 * 2, stream>>>(
      leaf_idx, nf_ids, embB, wN1, nf_b1, wN2, nf_b2, roots);

  leafmlp_k<<<RLEAF / 32 + 3, 256, 0, stream>>>(
      roots, leafperm, leafcnt, wL1, lf_b1, wL2, lf_b2, stmt);

  attn_k<<<1024, 128, 0, stream>>>(stmt, roots, th_emb, th_idx,
                                   he_W, he_b, hg_W, hg_b, ht_W, ht_b,
                                   (float*)d_out);
}

// Round 9
// 911.039 us; speedup vs baseline: 2.2379x; 1.3587x over previous
//
#include <hip/hip_runtime.h>
#include <math.h>

// RecursiveAttentiveEncoder — fused-tree MFMA, R9.
// R8 post-mortem: MR 64->32 doubled per-row weight traffic (full 196KB W1+W2
// L2 stream per group regardless of rows) and the 2-blocks/CU bet failed
// (occupancy stayed 11%) -> slower. R9 keeps R6's group geometry (TPB=32,
// MR=64, ~17.4k weight-stream groups total) and doubles waves INSIDE the
// block: 512 threads, 8 waves; phase1 = 2 m-tiles/wave, phase2 = 1. Per-wave
// acc halves (48 VGPR) -> no spill; 2 waves/SIMD resident by construction.
// Math identical to the verified engine (absmax 1.2e-4).

typedef unsigned short u16;
typedef unsigned int   u32;
typedef unsigned long long u64;
typedef __attribute__((ext_vector_type(8))) short v8s;   // 8 bf16 (4 VGPRs)
typedef __attribute__((ext_vector_type(4))) float f32x4; // MFMA acc

__device__ __forceinline__ float b2f(u16 u) { return __uint_as_float(((u32)u) << 16); }
__device__ __forceinline__ u16 f2b(float f) {
  f = (f == f) ? f : 0.f;                    // NaN squash (hygiene)
  u32 x = __float_as_uint(f);
  u32 r = x + 0x7fffu + ((x >> 16) & 1u);
  return (u16)(r >> 16);
}

#define NTREE 34816   // B*T_TREES = 1024*34
#define RLEAF 9216    // B*(GT_MAX+1)
#define TPB   32      // trees per block in tree_k

// tree_k LDS layout, u16 units (total 70672 u16 = 141344 B)
#define OFF_A  0      // 32 trees * 8 rows * 136 = 34816  (lvl0 out, lvl2 out)
#define OFF_B  34816  // 32 * 4 * 136 = 17408             (lvl1 out)
#define OFF_H  52224  // 64 rows * 264 = 16896            (phase-1 h scratch)
#define OFF_L  69120  // bin lists: 4 * 256               (u16 row ids)
#define OFF_LI 70144  // lvl0 leaf-idx pairs: 256*2 = 512
#define OFF_C  70656  // 4 int counters (16 u16)
#define SMEM_U16 70672

// ==================== leaf-stage expert sort ====================
__global__ __launch_bounds__(256) void leaf_perm_k(
    const int* __restrict__ lf, int* __restrict__ cnt, int* __restrict__ perm)
{
  const int gid = blockIdx.x * 256 + threadIdx.x;   // 36*256 = 9216 exact
  const int id = lf[gid];
  const int lane = threadIdx.x & 63;
  for (int e = 0; e < 3; ++e) {
    u64 m = __ballot(id == e);
    if (!m) continue;
    int leader = __builtin_ctzll(m);
    int bp = 0;
    if (lane == leader) bp = atomicAdd(&cnt[e], (int)__popcll(m));
    bp = __shfl(bp, leader);
    if (id == e)
      perm[e * RLEAF + bp + (int)__popcll(m & ((1ull << lane) - 1ull))] = gid;
  }
}

// ==================== weight convert+transpose (f32 -> bf16) ====================
__global__ __launch_bounds__(256) void transpose_k(
    const float* __restrict__ s0, const float* __restrict__ s1,
    const float* __restrict__ s2, const float* __restrict__ s3,
    const float* __restrict__ s4,
    u16* __restrict__ d0, u16* __restrict__ d1, u16* __restrict__ d2,
    u16* __restrict__ d3, u16* __restrict__ d4)
{
  int idx = blockIdx.x * 256 + threadIdx.x;
  if (idx < 262144) {                       // nf_W1 [4][256][256] -> [e][o][i]
    int e = idx >> 16, r = idx & 65535, o = r >> 8, i = r & 255;
    d0[idx] = f2b(s0[(e << 16) + (i << 8) + o]);
  } else if (idx < 393216) {                // nf_W2 [4][256][128] -> [4][128][256]
    int t = idx - 262144;
    int e = t >> 15, r = t & 32767, o = r >> 8, i = r & 255;
    d1[t] = f2b(s1[(e << 15) + (i << 7) + o]);
  } else if (idx < 786432) {                // lf_W1 [3][256][512] -> [3][512][256]
    int t = idx - 393216;
    int e = t >> 17, r = t & 131071, o = r >> 8, i = r & 255;
    d2[t] = f2b(s2[(e << 17) + (i << 9) + o]);
  } else if (idx < 983040) {                // lf_W2 [3][512][128] -> [3][128][512]
    int t = idx - 786432;
    int e = t >> 16, r = t & 65535, o = r >> 9, i = r & 511;
    d3[t] = f2b(s3[(e << 16) + (i << 7) + o]);
  } else if (idx < 1239040) {               // ent_emb [2000][128] f32 -> bf16
    int t = idx - 983040;
    d4[t] = f2b(s4[t]);
  }
}

// ==================== fused tree kernel ====================
// Block = 32 trees, 512 threads (8 waves), 141KB dynamic LDS, 1 block/CU.
// Per level: LDS-atomic expert sort -> per-expert 64-row groups ->
// fused relu(x@W1+b1)@W2+b2, h^T = W1t(A)*x^T(B), y^T = W2t(A)*h^T(B).
// Phase1: wave w owns m-tiles {2w, 2w+1} of 16; phase2: m-tile w of 8.
// Children of row r are src rows 2r, 2r+1.
__global__ __launch_bounds__(512, 1) void tree_k(
    const int* __restrict__ leaf, const int* __restrict__ nf,
    const u16* __restrict__ embB,
    const u16* __restrict__ W1t, const float* __restrict__ b1,
    const u16* __restrict__ W2t, const float* __restrict__ b2,
    u16* __restrict__ roots)
{
  extern __shared__ u16 smem[];
  int* lcnt = (int*)(smem + OFF_C);
  const int tid = threadIdx.x;
  const int w = tid >> 6, lane = tid & 63, lm = lane & 15, lq = lane >> 4;
  const int gt0 = blockIdx.x * TPB;

  const int nArr[4]  = {8, 4, 2, 1};
  const int ioArr[4] = {0, 8, 12, 14};
  const int soArr[4] = {0, OFF_A, OFF_B, OFF_A};
  const int doArr[4] = {OFF_A, OFF_B, OFF_A, 0};

  #pragma unroll
  for (int lvl = 0; lvl < 4; ++lvl) {
    const int nn = nArr[lvl];
    const int R  = TPB * nn;                 // 256,128,64,32 rows
    const int io = ioArr[lvl];
    const int so = soArr[lvl];
    const int dox = doArr[lvl];

    // ---- local expert sort (and lvl0 leaf-idx stash) ----
    __syncthreads();                        // prior level's reads complete
    if (tid < 4) lcnt[tid] = 0;
    __syncthreads();
    if (tid < R) {
      int t = tid / nn, node = tid - t * nn;
      int e = nf[(gt0 + t) * 15 + io + node] & 3;
      int p = atomicAdd(&lcnt[e], 1);
      smem[OFF_L + (e << 8) + p] = (u16)tid;  // row id r == tid
      if (lvl == 0) {
        int ia = leaf[(gt0 + t) * 16 + 2 * node];
        int ib = leaf[(gt0 + t) * 16 + 2 * node + 1];
        ia = ia < 0 ? 0 : (ia > 1999 ? 1999 : ia);   // V_ENT=2000
        ib = ib < 0 ? 0 : (ib > 1999 ? 1999 : ib);
        smem[OFF_LI + 2 * tid]     = (u16)ia;
        smem[OFF_LI + 2 * tid + 1] = (u16)ib;
      }
    }
    __syncthreads();

    // ---- per-expert 64-row groups ----
    for (int e = 0; e < 4; ++e) {
      const int ce = lcnt[e];               // uniform (post-barrier)
      const u16* __restrict__ Wb  = W1t + e * 65536;   // [256 o][256 i]
      const u16* __restrict__ W2b = W2t + e * 32768;   // [128 o][256 i]
      const float* b1b = b1 + e * 256;
      const float* b2b = b2 + e * 128;

      for (int g = 0; g < ce; g += 64) {
        int rloc[4]; bool val[4];
        const u16 *gpa[4], *gpb[4];
        int oa[4], ob[4];
        #pragma unroll
        for (int n = 0; n < 4; ++n) {
          int li = g + n * 16 + lm;
          int lic = li < ce ? li : ce - 1;   // clamp partial tile
          int r = smem[OFF_L + (e << 8) + lic];
          val[n] = li < ce;
          rloc[n] = r;
          if (lvl == 0) {
            gpa[n] = embB + (size_t)smem[OFF_LI + 2 * r] * 128;
            gpb[n] = embB + (size_t)smem[OFF_LI + 2 * r + 1] * 128;
          } else {
            oa[n] = so + (2 * r) * 136;      // children rows 2r, 2r+1
            ob[n] = so + (2 * r + 1) * 136;
          }
        }

        // ---- phase 1: h^T = W1t * x^T, +b1, relu -> OFF_H ----
        f32x4 acc[2][4];
        #pragma unroll
        for (int m = 0; m < 2; ++m)
          #pragma unroll
          for (int n = 0; n < 4; ++n)
            acc[m][n] = f32x4{0.f, 0.f, 0.f, 0.f};

        #pragma unroll
        for (int k = 0; k < 8; ++k) {        // K = 256
          const int ko = k * 32 + lq * 8;
          v8s bfr[4];
          if (lvl == 0) {
            #pragma unroll
            for (int n = 0; n < 4; ++n)
              bfr[n] = *(const v8s*)((ko < 128) ? (gpa[n] + ko) : (gpb[n] + (ko - 128)));
          } else {
            #pragma unroll
            for (int n = 0; n < 4; ++n)
              bfr[n] = *(const v8s*)(smem + ((ko < 128) ? (oa[n] + ko) : (ob[n] + (ko - 128))));
          }
          #pragma unroll
          for (int m = 0; m < 2; ++m) {
            const v8s af = *(const v8s*)(Wb + (size_t)((w * 2 + m) * 16 + lm) * 256 + ko);
            #pragma unroll
            for (int n = 0; n < 4; ++n)
              acc[m][n] = __builtin_amdgcn_mfma_f32_16x16x32_bf16(af, bfr[n], acc[m][n], 0, 0, 0);
          }
        }
        #pragma unroll
        for (int m = 0; m < 2; ++m) {
          const int f = (w * 2 + m) * 16 + lq * 4;
          float bb0 = b1b[f], bb1 = b1b[f + 1], bb2 = b1b[f + 2], bb3 = b1b[f + 3];
          #pragma unroll
          for (int n = 0; n < 4; ++n) {
            union { u16 h[4]; uint2 v; } pk;
            f32x4 a = acc[m][n];
            pk.h[0] = f2b(fmaxf(a.x + bb0, 0.f));
            pk.h[1] = f2b(fmaxf(a.y + bb1, 0.f));
            pk.h[2] = f2b(fmaxf(a.z + bb2, 0.f));
            pk.h[3] = f2b(fmaxf(a.w + bb3, 0.f));
            *(uint2*)&smem[OFF_H + (n * 16 + lm) * 264 + f] = pk.v;
          }
        }
        __syncthreads();

        // ---- phase 2: y^T = W2t * h^T (wave w -> m-tile w of 8) ----
        f32x4 a2[4];
        #pragma unroll
        for (int n = 0; n < 4; ++n)
          a2[n] = f32x4{0.f, 0.f, 0.f, 0.f};

        #pragma unroll
        for (int k = 0; k < 8; ++k) {
          const int ko = k * 32 + lq * 8;
          v8s bfr[4];
          #pragma unroll
          for (int n = 0; n < 4; ++n)
            bfr[n] = *(const v8s*)(smem + OFF_H + (n * 16 + lm) * 264 + ko);
          const v8s af = *(const v8s*)(W2b + (size_t)(w * 16 + lm) * 256 + ko);
          #pragma unroll
          for (int n = 0; n < 4; ++n)
            a2[n] = __builtin_amdgcn_mfma_f32_16x16x32_bf16(af, bfr[n], a2[n], 0, 0, 0);
        }
        {
          const int f = w * 16 + lq * 4;
          float bb0 = b2b[f], bb1 = b2b[f + 1], bb2 = b2b[f + 2], bb3 = b2b[f + 3];
          #pragma unroll
          for (int n = 0; n < 4; ++n) {
            if (val[n]) {
              union { u16 h[4]; uint2 v; } pk;
              f32x4 a = a2[n];
              pk.h[0] = f2b(a.x + bb0);
              pk.h[1] = f2b(a.y + bb1);
              pk.h[2] = f2b(a.z + bb2);
              pk.h[3] = f2b(a.w + bb3);
              if (lvl < 3)
                *(uint2*)&smem[dox + rloc[n] * 136 + f] = pk.v;
              else
                *(uint2*)(roots + (size_t)(gt0 + rloc[n]) * 128 + f) = pk.v;
            }
          }
        }
        __syncthreads();                    // H reused by next group
      }
    }
  }
}

// ==================== leaf expert MLP (global roots -> stmt) ====================
__global__ __launch_bounds__(256, 2) void leafmlp_k(
    const u16* __restrict__ src,
    const int* __restrict__ perm, const int* __restrict__ cnt,
    const u16* __restrict__ W1t, const float* __restrict__ b1,
    const u16* __restrict__ W2t, const float* __restrict__ b2,
    u16* __restrict__ dst)
{
  constexpr int HID = 512, MR = 32;
  constexpr int HSTR = HID + 8;
  constexpr int NT = MR / 16;         // 2
  constexpr int MT1 = HID / 64;       // 8
  __shared__ __align__(16) u16 hs[MR * HSTR];

  int bin = -1, tile = 0, cb = 0;
  {
    int rem = blockIdx.x;
    #pragma unroll
    for (int e = 0; e < 3; ++e) {
      int ce = cnt[e];
      int tt = (ce + MR - 1) / MR;
      if (bin < 0) {
        if (rem < tt) { bin = e; tile = rem; cb = ce; }
        else rem -= tt;
      }
    }
  }
  if (bin < 0) return;
  const int rbase = tile * MR;
  const int tid = threadIdx.x;
  const int w  = tid >> 6;
  const int lane = tid & 63;
  const int lm = lane & 15;
  const int lq = lane >> 4;

  const u16* rpa[NT]; const u16* rpb[NT]; int rowid[NT];
  #pragma unroll
  for (int n = 0; n < NT; ++n) {
    int rl = rbase + n * 16 + lm;
    int rlc = rl < cb ? rl : (cb - 1);
    int rc = perm[(size_t)bin * RLEAF + rlc];
    rc = rc < 0 ? 0 : (rc >= RLEAF ? RLEAF - 1 : rc);
    rowid[n] = (rl < cb) ? rc : -1;
    int bq = rc / 9, g = rc - bq * 9;
    rpa[n] = src + ((size_t)bq * 34 + 16 + 2 * g) * 128;
    rpb[n] = rpa[n] + 128;
  }

  const u16* __restrict__ Wb = W1t + (size_t)bin * HID * 256;
  f32x4 acc[MT1][NT];
  #pragma unroll
  for (int m = 0; m < MT1; ++m)
    #pragma unroll
    for (int n = 0; n < NT; ++n)
      acc[m][n] = f32x4{0.f, 0.f, 0.f, 0.f};

  #pragma unroll
  for (int k = 0; k < 8; ++k) {
    const int ko = k * 32 + lq * 8;
    v8s bfr[NT];
    #pragma unroll
    for (int n = 0; n < NT; ++n) {
      const u16* p = (ko < 128) ? (rpa[n] + ko) : (rpb[n] + (ko - 128));
      bfr[n] = *(const v8s*)p;
    }
    #pragma unroll
    for (int m = 0; m < MT1; ++m) {
      const v8s af = *(const v8s*)(Wb + (size_t)((w * MT1 + m) * 16 + lm) * 256 + ko);
      #pragma unroll
      for (int n = 0; n < NT; ++n)
        acc[m][n] = __builtin_amdgcn_mfma_f32_16x16x32_bf16(af, bfr[n], acc[m][n], 0, 0, 0);
    }
  }
  const float* b1b = b1 + bin * HID;
  #pragma unroll
  for (int m = 0; m < MT1; ++m) {
    const int f = (w * MT1 + m) * 16 + lq * 4;
    float bb0 = b1b[f], bb1 = b1b[f + 1], bb2 = b1b[f + 2], bb3 = b1b[f + 3];
    #pragma unroll
    for (int n = 0; n < NT; ++n) {
      union { u16 h[4]; uint2 v; } pk;
      f32x4 a = acc[m][n];
      pk.h[0] = f2b(fmaxf(a.x + bb0, 0.f));
      pk.h[1] = f2b(fmaxf(a.y + bb1, 0.f));
      pk.h[2] = f2b(fmaxf(a.z + bb2, 0.f));
      pk.h[3] = f2b(fmaxf(a.w + bb3, 0.f));
      *(uint2*)&hs[(n * 16 + lm) * HSTR + f] = pk.v;
    }
  }
  __syncthreads();

  const u16* __restrict__ W2b = W2t + (size_t)bin * 128 * HID;
  f32x4 acc2[2][NT];
  #pragma unroll
  for (int m = 0; m < 2; ++m)
    #pragma unroll
    for (int n = 0; n < NT; ++n)
      acc2[m][n] = f32x4{0.f, 0.f, 0.f, 0.f};

  #pragma unroll 4
  for (int k = 0; k < HID / 32; ++k) {
    const int ko = k * 32 + lq * 8;
    v8s bfr[NT];
    #pragma unroll
    for (int n = 0; n < NT; ++n)
      bfr[n] = *(const v8s*)&hs[(n * 16 + lm) * HSTR + ko];
    #pragma unroll
    for (int m = 0; m < 2; ++m) {
      const v8s af = *(const v8s*)(W2b + (size_t)((w * 2 + m) * 16 + lm) * HID + ko);
      #pragma unroll
      for (int n = 0; n < NT; ++n)
        acc2[m][n] = __builtin_amdgcn_mfma_f32_16x16x32_bf16(af, bfr[n], acc2[m][n], 0, 0, 0);
    }
  }
  const float* b2b = b2 + bin * 128;
  #pragma unroll
  for (int m = 0; m < 2; ++m) {
    const int f = (w * 2 + m) * 16 + lq * 4;
    float bb0 = b2b[f], bb1 = b2b[f + 1], bb2 = b2b[f + 2], bb3 = b2b[f + 3];
    #pragma unroll
    for (int n = 0; n < NT; ++n) {
      if (rowid[n] >= 0) {
        union { u16 h[4]; uint2 v; } pk;
        f32x4 a = acc2[m][n];
        pk.h[0] = f2b(a.x + bb0);
        pk.h[1] = f2b(a.y + bb1);
        pk.h[2] = f2b(a.z + bb2);
        pk.h[3] = f2b(a.w + bb3);
        *(uint2*)(dst + (size_t)rowid[n] * 128 + f) = pk.v;
      }
    }
  }
}

// ==================== attention + concat (fp32) ====================
__global__ __launch_bounds__(128) void attn_k(
    const u16* __restrict__ stmt, const u16* __restrict__ roots,
    const float* __restrict__ themb, const int* __restrict__ thidx,
    const float* __restrict__ wHe, const float* __restrict__ bHe,
    const float* __restrict__ wHg, const float* __restrict__ bHg,
    const float* __restrict__ wHt, const float* __restrict__ bHt,
    float* __restrict__ out)
{
  const int b = blockIdx.x, t = threadIdx.x;   // 128 threads
  __shared__ float obj_s[128], q_s[128], keys_s[16 * 132], a_s[16];

  const float obj = b2f(stmt[((size_t)b * 9 + 8) * 128 + t]);
  obj_s[t] = obj;
  out[(size_t)b * 512 + t] = obj;              // obj passthrough
  __syncthreads();

  for (int a = 0; a < 3; ++a) {               // 0: gt_ctx, 1: ent_ctx, 2: th_ctx
    int cntk;
    const float *Wt, *bv;
    if (a == 0) {
      cntk = 8; Wt = wHg; bv = bHg;
      for (int j = 0; j < 8; ++j)
        keys_s[j * 132 + t] = b2f(stmt[((size_t)b * 9 + j) * 128 + t]);
    } else if (a == 1) {
      cntk = 16; Wt = wHe; bv = bHe;
      for (int j = 0; j < 16; ++j)
        keys_s[j * 132 + t] = b2f(roots[((size_t)b * 34 + j) * 128 + t]);
    } else {
      cntk = 8; Wt = wHt; bv = bHt;           // TH_MAX = 8
      for (int j = 0; j < 8; ++j) {
        int ti = thidx[b * 8 + j] & 31;        // V_TH = 32
        keys_s[j * 132 + t] = themb[(size_t)ti * 128 + t];
      }
    }
    float qa = bv[t];
    for (int k = 0; k < 128; ++k) qa += obj_s[k] * Wt[k * 128 + t];
    q_s[t] = (qa == qa) ? qa : 0.f;
    __syncthreads();
    if (t < cntk) {
      float sc = 0.f;
      for (int k = 0; k < 128; ++k) sc += keys_s[t * 132 + k] * q_s[k];
      a_s[t] = (sc == sc) ? sc : 0.f;
    }
    __syncthreads();
    if (t == 0) {
      float mx = a_s[0];
      for (int j = 1; j < cntk; ++j) mx = fmaxf(mx, a_s[j]);
      float sm = 0.f;
      for (int j = 0; j < cntk; ++j) { float e = expf(a_s[j] - mx); a_s[j] = e; sm += e; }
      float inv = 1.f / sm;
      for (int j = 0; j < cntk; ++j) a_s[j] *= inv;
    }
    __syncthreads();
    float c = 0.f;
    for (int j = 0; j < cntk; ++j) c += a_s[j] * keys_s[j * 132 + t];
    out[(size_t)b * 512 + 128 * (a + 1) + t] = c;
    __syncthreads();
  }
}

// ==================== launch ====================
extern "C" void kernel_launch(void* const* d_in, const int* in_sizes, int n_in,
                              void* d_out, int out_size, void* d_ws, size_t ws_size,
                              hipStream_t stream)
{
  const int*   leaf_idx = (const int*)d_in[0];
  const int*   nf_ids   = (const int*)d_in[1];
  const int*   lf_ids   = (const int*)d_in[2];
  const int*   th_idx   = (const int*)d_in[3];
  const float* ent_emb  = (const float*)d_in[4];
  const float* th_emb   = (const float*)d_in[5];
  const float* nf_W1 = (const float*)d_in[6];
  const float* nf_b1 = (const float*)d_in[7];
  const float* nf_W2 = (const float*)d_in[8];
  const float* nf_b2 = (const float*)d_in[9];
  const float* lf_W1 = (const float*)d_in[10];
  const float* lf_b1 = (const float*)d_in[11];
  const float* lf_W2 = (const float*)d_in[12];
  const float* lf_b2 = (const float*)d_in[13];
  const float* he_W = (const float*)d_in[14];
  const float* he_b = (const float*)d_in[15];
  const float* hg_W = (const float*)d_in[16];
  const float* hg_b = (const float*)d_in[17];
  const float* ht_W = (const float*)d_in[18];
  const float* ht_b = (const float*)d_in[19];

  char* ws = (char*)d_ws;
  size_t off = 0;
  auto take = [&](size_t bytes) -> char* {
    char* p = ws + off;
    off = (off + bytes + 255) & ~(size_t)255;
    return p;
  };
  int* leafcnt  = (int*)take(256);
  int* leafperm = (int*)take((size_t)3 * RLEAF * 4);      // 110.6 KB
  u16* wN1  = (u16*)take((size_t)4 * 256 * 256 * 2);      // 512 KB
  u16* wN2  = (u16*)take((size_t)4 * 128 * 256 * 2);      // 256 KB
  u16* wL1  = (u16*)take((size_t)3 * 512 * 256 * 2);      // 786 KB
  u16* wL2  = (u16*)take((size_t)3 * 128 * 512 * 2);      // 393 KB
  u16* embB = (u16*)take((size_t)2000 * 128 * 2);         // 512 KB
  u16* roots = (u16*)take((size_t)NTREE * 128 * 2);       // 8.91 MB
  u16* stmt  = (u16*)take((size_t)RLEAF * 128 * 2);       // 2.36 MB
  // total ~13.9 MB

  hipMemsetAsync(leafcnt, 0, 32, stream);
  transpose_k<<<4840, 256, 0, stream>>>(nf_W1, nf_W2, lf_W1, lf_W2, ent_emb,
                                        wN1, wN2, wL1, wL2, embB);
  leaf_perm_k<<<36, 256, 0, stream>>>(lf_ids, leafcnt, leafperm);

  tree_k<<<NTREE / TPB, 512, SMEM_U16 * 2, stream>>>(
      leaf_idx, nf_ids, embB, wN1, nf_b1, wN2, nf_b2, roots);

  leafmlp_k<<<RLEAF / 32 + 3, 256, 0, stream>>>(
      roots, leafperm, leafcnt, wL1, lf_b1, wL2, lf_b2, stmt);

  attn_k<<<1024, 128, 0, stream>>>(stmt, roots, th_emb, th_idx,
                                   he_W, he_b, hg_W, hg_b, ht_W, ht_b,
                                   (float*)d_out);
}